// Round 7
// baseline (214.849 us; speedup 1.0000x reference)
//
#include <hip/hip_runtime.h>
#include <hip/hip_bf16.h>
#include <utility>

#define KVOL 27

using bf16 = __hip_bfloat16;
typedef __attribute__((ext_vector_type(8))) short short8;
typedef __attribute__((ext_vector_type(4))) short short4v;
typedef __attribute__((ext_vector_type(4))) float f32x4;
typedef __attribute__((ext_vector_type(4))) int int4v;

// async global->LDS 16B DMA; lds base is wave-uniform, HW writes lane i at base+i*16
__device__ __forceinline__ void async16(const void* g, void* l) {
    __builtin_amdgcn_global_load_lds(
        (const __attribute__((address_space(1))) void*)g,
        (__attribute__((address_space(3))) void*)l, 16, 0, 0);
}

template <class F, int... Is>
__device__ __forceinline__ void static_for_impl(F&& f, std::integer_sequence<int, Is...>) {
    (f(std::integral_constant<int, Is>{}), ...);
}
template <int N, class F>
__device__ __forceinline__ void static_for(F&& f) {
    static_for_impl(static_cast<F&&>(f), std::make_integer_sequence<int, N>{});
}

// vmcnt immediate guaranteeing stageA(t) complete (R3-proven form; the
// prologue branch is the order-robust lower bound on ops younger than SA(t)).
template <int NT, int D, int BR, int NI, int NB>
constexpr int waitA(int t) {
    int s = ((t + D < NT) ? NI : 0);            // SA(t+D), issued before the wait
    if (t < D) {
        for (int j = 0; j < t; ++j)
            s += ((j + D < NT) ? NI : 0) + ((j + BR < NT) ? NB : 0);
    } else {
        s += ((t - D + BR < NT) ? NB : 0);      // loadB tail of SA(t)'s region
        for (int j = t - D + 1; j < t; ++j)
            s += ((j + D < NT) ? NI : 0) + ((j + BR < NT) ? NB : 0);
    }
    return s;
}

// ---------------- fused mnc prepass for 4 (nbr,mask) pairs + zero page ----
__global__ __launch_bounds__(256) void mnc_all_kernel(
    const int* __restrict__ nbr0, const int* __restrict__ mask0, int* __restrict__ mnc0, int n0,
    const int* __restrict__ nbr1, const int* __restrict__ mask1, int* __restrict__ mnc1, int n1,
    const int* __restrict__ nbr2, const int* __restrict__ mask2, int* __restrict__ mnc2, int n2,
    const int* __restrict__ nbr3, const int* __restrict__ mask3, int* __restrict__ mnc3, int n3,
    int* __restrict__ zp) {
    if (blockIdx.x == 0 && threadIdx.x < 8) {
        int4v z = {0, 0, 0, 0};
        reinterpret_cast<int4v*>(zp)[threadIdx.x] = z;  // 128B zero page
    }
    int t4 = (blockIdx.x * 256 + threadIdx.x) * 4;
    const int* nbr; const int* mask; int* dst; int off;
    if (t4 < n0) { nbr = nbr0; mask = mask0; dst = mnc0; off = t4; }
    else if ((t4 -= n0) < n1) { nbr = nbr1; mask = mask1; dst = mnc1; off = t4; }
    else if ((t4 -= n1) < n2) { nbr = nbr2; mask = mask2; dst = mnc2; off = t4; }
    else if ((t4 -= n2) < n3) { nbr = nbr3; mask = mask3; dst = mnc3; off = t4; }
    else return;
    const int4v nb = *reinterpret_cast<const int4v*>(nbr + off);
    const int4v mk = *reinterpret_cast<const int4v*>(mask + off);
    int4v r;
    r.x = mk.x ? nb.x : -1;
    r.y = mk.y ? nb.y : -1;
    r.z = mk.z ? nb.z : -1;
    r.w = mk.w ? nb.w : -1;
    *reinterpret_cast<int4v*>(dst + off) = r;
}

// ---------------- fp32 -> bf16 convert, pad 16ch -> 32ch ----------------
__global__ __launch_bounds__(256) void cvt_pad_kernel(
    const float* __restrict__ in, bf16* __restrict__ out, int N0) {
    const int t = blockIdx.x * blockDim.x + threadIdx.x;
    if (t >= N0 * 8) return;
    const int row = t >> 3;
    const int c4 = (t & 7) * 4;
    short4v o = {0, 0, 0, 0};
    if (c4 < 16) {
        const float4 v = *reinterpret_cast<const float4*>(in + (size_t)row * 16 + c4);
        bf16 b0 = __float2bfloat16(v.x); o.x = *reinterpret_cast<short*>(&b0);
        bf16 b1 = __float2bfloat16(v.y); o.y = *reinterpret_cast<short*>(&b1);
        bf16 b2 = __float2bfloat16(v.z); o.z = *reinterpret_cast<short*>(&b2);
        bf16 b3 = __float2bfloat16(v.w); o.w = *reinterpret_cast<short*>(&b3);
    }
    *reinterpret_cast<short4v*>(out + (size_t)row * 32 + c4) = o;
}

// ---------------- fused weight pack (all 10 weight tensors) ----------------
struct PackJobs {
    const float* W[10];
    bf16* Wp[10];
    int cin[10];
    int cout[10];
    int kvol[10];
    int start[11];
};

__global__ __launch_bounds__(256) void pack_all_kernel(PackJobs J, int total) {
    const int t = blockIdx.x * 256 + threadIdx.x;
    if (t >= total) return;
    int jb = 9;
#pragma unroll
    for (int q = 8; q >= 0; --q) if (t < J.start[q + 1]) jb = q;
    const int u = t - J.start[jb];
    const int CIN = J.cin[jb], COUT = J.cout[jb], KV = J.kvol[jb];
    const int CINP = CIN < 32 ? 32 : CIN;
    const int NCH = CINP / 32;
    const int e = u & 7;
    const int lane = (u >> 3) & 63;
    int rest = u >> 9;
    const int c = rest % NCH; rest /= NCH;
    const int k = rest % KV;
    const int ct = rest / KV;
    const int cout = ct * 16 + (lane & 15);
    const int cin = c * 32 + (lane >> 4) * 8 + e;
    const float v = (cin < CIN) ? J.W[jb][((size_t)k * CIN + cin) * COUT + cout] : 0.f;
    J.Wp[jb][u] = __float2bfloat16(v);
}

// ---------------- sparse conv: async-DMA staged, counted-vmcnt pipeline ---
// WPB independent waves/block; wave owns RT*16 rows x (CTW*16) cols over all
// 27 taps. A staged via global_load_lds (whole-line mapping, XOR swizzle on
// the per-lane GLOBAL source; linear LDS dest). Masked taps -> zero page.
// D-deep tap pipeline, compile-time vmcnt counts; B ring (BR>=D) refilled at
// region TAIL. No __syncthreads anywhere.
template <int CIN, int COUT, int CTW, int RT, int WPB, int D, int BR, int MINW, bool OUT_F32>
__global__ __launch_bounds__(WPB * 64, MINW) void conv_async_kernel(
    const bf16* __restrict__ x, const bf16* __restrict__ Wp,
    const int* __restrict__ mnc, const bf16* __restrict__ zp,
    void* __restrict__ outv, int Nout) {
    constexpr int NCH = CIN / 32;              // CIN in {32, 64}
    constexpr int CH  = CIN / 8;               // 16B chunks per row
    constexpr int RPI = 64 / CH;               // rows staged per instr
    constexpr int NI  = RT * NCH;              // stage instrs per tap
    constexpr int NB  = CTW * NCH;             // B loads per tap
    constexpr int ROWS = RT * 16;
    constexpr int SLOT = ROWS * CIN * 2;       // bytes per tap tile
    constexpr int NS = D + 1;
    constexpr int TPL = 64 / ROWS;             // taps per packed mnc load
    constexpr int NL = (KVOL + TPL - 1) / TPL;
    constexpr int CTG = (COUT / 16) / CTW;
    constexpr int NT = KVOL;

    __shared__ __align__(16) char smem[WPB][NS * SLOT];

    const int w = threadIdx.x >> 6;
    const int lane = threadIdx.x & 63;
    const int bid = blockIdx.x;
    const int rg = bid / CTG;
    const int cg = bid - rg * CTG;
    const int rowbase = rg * (WPB * ROWS) + w * ROWS;
    if (rowbase >= Nout) return;
    const int r = lane & 15;
    const int g = lane >> 4;
    char* const sb = smem[w];

    // packed mnc: load p covers taps p*TPL..p*TPL+TPL-1; lane = tp*ROWS + row
    int mnw[NL];
    {
        const int row = rowbase + (lane % ROWS);
        const int rc = (row < Nout) ? row : (Nout - 1);
#pragma unroll
        for (int p = 0; p < NL; ++p) {
            const int k = p * TPL + (lane / ROWS);
            int v = -1;
            if (k < NT) {
                const int vv = mnc[(size_t)k * Nout + rc];
                v = (row < Nout) ? vv : -1;
            }
            mnw[p] = v;
        }
    }

    short8 bring[BR][CTW][NCH];
    auto loadB = [&](int t) {
#pragma unroll
        for (int cw = 0; cw < CTW; ++cw) {
            const int ct = cg * CTW + cw;
#pragma unroll
            for (int c = 0; c < NCH; ++c)
                bring[t % BR][cw][c] = *reinterpret_cast<const short8*>(
                    Wp + (((size_t)ct * KVOL + t) * NCH + c) * 512 + lane * 8);
        }
    };

    auto stageA = [&](int t) {
        char* const dst = sb + (t % NS) * SLOT;
        const int mw = mnw[t / TPL];
        const int tb = (t % TPL) * ROWS;
        const int rl0 = lane / CH;             // row within stage instr
        const int ch0 = lane % CH;             // chunk within row
#pragma unroll
        for (int q = 0; q < NI; ++q) {
            const int rl = q * RPI + rl0;      // row within tile
            const int j = __builtin_amdgcn_ds_bpermute((tb + rl) * 4, mw);
            const int ch = (ch0 ^ (rl & (CH - 1))) * 8;        // XOR swizzle
            const bf16* src = (j >= 0) ? (x + (size_t)j * CIN) : zp;
            async16(src + ch, dst + q * 1024);
        }
    };

    f32x4 acc[RT][CTW];
#pragma unroll
    for (int rt = 0; rt < RT; ++rt)
#pragma unroll
        for (int cw = 0; cw < CTW; ++cw) {
            f32x4 z = {0.f, 0.f, 0.f, 0.f};
            acc[rt][cw] = z;
        }

    // prologue: BR B tiles first (older than all SA), then D A tiles
#pragma unroll
    for (int t = 0; t < BR; ++t) loadB(t);
#pragma unroll
    for (int t = 0; t < D; ++t) stageA(t);

    static_for<NT>([&](auto tc) {
        constexpr int t = decltype(tc)::value;
        // all prior ds_reads retired before their slot is re-DMA'd
        asm volatile("s_waitcnt lgkmcnt(0)" ::: "memory");
        if constexpr (t + D < NT) stageA(t + D);
        constexpr int WN = waitA<NT, D, BR, NI, NB>(t);
        asm volatile("s_waitcnt vmcnt(%0)" :: "n"(WN) : "memory");
        const char* sp = sb + (t % NS) * SLOT;
        short8 af[RT][NCH];
#pragma unroll
        for (int rt = 0; rt < RT; ++rt)
#pragma unroll
            for (int c = 0; c < NCH; ++c) {
                const int R = rt * 16 + r;
                const int cc = c * 4 + g;
                const int off = R * (CIN * 2) + ((cc ^ (R & (CH - 1))) * 16);
                af[rt][c] = *reinterpret_cast<const short8*>(sp + off);
            }
#pragma unroll
        for (int c = 0; c < NCH; ++c)
#pragma unroll
            for (int cw = 0; cw < CTW; ++cw)
#pragma unroll
                for (int rt = 0; rt < RT; ++rt)
                    acc[rt][cw] = __builtin_amdgcn_mfma_f32_16x16x32_bf16(
                        af[rt][c], bring[t % BR][cw][c], acc[rt][cw], 0, 0, 0);
        // ring refill AFTER last read of this slot (WAR, not RAW)
        if constexpr (t + BR < NT) loadB(t + BR);
    });

    // epilogue: wave owns its tile outright
#pragma unroll
    for (int rt = 0; rt < RT; ++rt)
#pragma unroll
        for (int cw = 0; cw < CTW; ++cw) {
            const int col = (cg * CTW + cw) * 16 + r;
#pragma unroll
            for (int i = 0; i < 4; ++i) {
                const int rowo = rowbase + rt * 16 + g * 4 + i;
                if (rowo < Nout) {
                    const float v = fmaxf(acc[rt][cw][i], 0.f);
                    if (OUT_F32) ((float*)outv)[(size_t)rowo * COUT + col] = v;
                    else ((bf16*)outv)[(size_t)rowo * COUT + col] = __float2bfloat16(v);
                }
            }
        }
}

// ---------------- decoder merge via MFMA ----------------
template <int C>
__global__ __launch_bounds__(256) void merge_mfma_kernel(
    const bf16* __restrict__ xb, const bf16* __restrict__ xl,
    const bf16* __restrict__ Wmp, bf16* __restrict__ out, int N) {
    constexpr int NCH = 2 * C / 32;
    constexpr int CT = C / 16;
    constexpr int CTW = 2;
    constexpr int CTG = CT / CTW;

    const int wid = blockIdx.x * (blockDim.x >> 6) + (threadIdx.x >> 6);
    const int lane = threadIdx.x & 63;
    const int rg = wid / CTG;
    const int cg = wid - rg * CTG;
    const int rowbase = rg * 16;
    if (rowbase >= N) return;
    const int r = lane & 15;
    const int g = lane >> 4;

    short8 a[NCH];
    const int arow = (rowbase + r < N) ? (rowbase + r) : (N - 1);
#pragma unroll
    for (int c = 0; c < NCH; ++c) {
        const int kbase = c * 32 + g * 8;
        const bf16* src = (kbase < C) ? (xb + (size_t)arow * C + kbase)
                                      : (xl + (size_t)arow * C + (kbase - C));
        a[c] = *reinterpret_cast<const short8*>(src);
    }

    f32x4 acc[CTW];
#pragma unroll
    for (int cw = 0; cw < CTW; ++cw) {
        f32x4 z = {0.f, 0.f, 0.f, 0.f};
        acc[cw] = z;
#pragma unroll
        for (int c = 0; c < NCH; ++c) {
            const size_t off = ((size_t)(cg * CTW + cw) * NCH + c) * 512 + lane * 8;
            const short8 b = *reinterpret_cast<const short8*>(Wmp + off);
            acc[cw] = __builtin_amdgcn_mfma_f32_16x16x32_bf16(a[c], b, acc[cw], 0, 0, 0);
        }
    }

#pragma unroll
    for (int cw = 0; cw < CTW; ++cw) {
        const int j = (cg * CTW + cw) * 16 + r;
#pragma unroll
        for (int i = 0; i < 4; ++i) {
            const int row = rowbase + g * 4 + i;
            if (row < N) {
                const float m = fmaxf(acc[cw][i], 0.f);
                const bf16* src = (2 * j < C) ? (xb + (size_t)row * C + 2 * j)
                                              : (xl + (size_t)row * C + (2 * j - C));
                const float red = __bfloat162float(src[0]) + __bfloat162float(src[1]);
                out[(size_t)row * C + j] = __float2bfloat16(m + red);
            }
        }
    }
}

// ---------------- host ----------------
template <int CIN, int COUT, int CTW, int RT, int WPB, int D, int BR, int MINW, bool OF32>
static void launch_conv(const bf16* x, const bf16* Wp, const int* mnc, const bf16* zp,
                        void* out, int Nout, hipStream_t s) {
    constexpr int CTG = (COUT / 16) / CTW;
    constexpr int BROWS = WPB * RT * 16;
    const int RG = (Nout + BROWS - 1) / BROWS;
    conv_async_kernel<CIN, COUT, CTW, RT, WPB, D, BR, MINW, OF32>
        <<<RG * CTG, WPB * 64, 0, s>>>(x, Wp, mnc, zp, out, Nout);
}

template <int C>
static void launch_merge(const bf16* xb, const bf16* xl, const bf16* Wmp,
                         bf16* out, int N, hipStream_t s) {
    constexpr int CTG = (C / 16) / 2;
    const int RG = (N + 15) / 16;
    const int waves = RG * CTG;
    const int blocks = (waves + 3) / 4;
    merge_mfma_kernel<C><<<blocks, 256, 0, s>>>(xb, xl, Wmp, out, N);
}

static size_t align_up(size_t v) { return (v + 255) & ~(size_t)255; }

extern "C" void kernel_launch(void* const* d_in, const int* in_sizes, int n_in,
                              void* d_out, int out_size, void* d_ws, size_t ws_size,
                              hipStream_t stream) {
    const float* feat     = (const float*)d_in[0];
    const int*   nbr0     = (const int*)d_in[1];
    const int*   mask0    = (const int*)d_in[2];
    const int*   nbr1     = (const int*)d_in[3];
    const int*   mask1    = (const int*)d_in[4];
    const int*   nbr_down = (const int*)d_in[5];
    const int*   mask_down= (const int*)d_in[6];
    const int*   nbr_up   = (const int*)d_in[7];
    const int*   mask_up  = (const int*)d_in[8];
    const float* W_in     = (const float*)d_in[9];
    const float* W_enc1   = (const float*)d_in[10];
    const float* W_down   = (const float*)d_in[11];
    const float* W_enc2   = (const float*)d_in[12];
    const float* W_lat2   = (const float*)d_in[13];
    const float* W_merge2 = (const float*)d_in[14];
    const float* W_up2    = (const float*)d_in[15];
    const float* W_lat1   = (const float*)d_in[16];
    const float* W_merge1 = (const float*)d_in[17];
    const float* W_up1    = (const float*)d_in[18];

    const int N0 = in_sizes[0] / 16;
    const int N1 = in_sizes[3] / KVOL;

    char* p = (char*)d_ws;
    auto carve = [&](size_t bytes) { char* q = p; p += align_up(bytes); return q; };

    bf16* featb = (bf16*)carve((size_t)N0 * 32 * 2);   // padded to 32 ch
    bf16* x0    = (bf16*)carve((size_t)N0 * 32 * 2);
    bf16* e1    = (bf16*)carve((size_t)N0 * 32 * 2);
    bf16* xd    = (bf16*)carve((size_t)N1 * 64 * 2);
    bf16* e2    = (bf16*)carve((size_t)N1 * 64 * 2);
    bf16* xl2   = (bf16*)carve((size_t)N1 * 64 * 2);
    bf16* m2    = (bf16*)carve((size_t)N1 * 64 * 2);
    bf16* u2    = (bf16*)carve((size_t)N0 * 32 * 2);
    bf16* xl1   = (bf16*)carve((size_t)N0 * 32 * 2);
    bf16* m1    = (bf16*)carve((size_t)N0 * 32 * 2);
    bf16* zp    = (bf16*)carve(256);                   // zero page (128B used)

    int* mnc0 = (int*)carve((size_t)KVOL * N0 * 4);
    int* mnc1 = (int*)carve((size_t)KVOL * N1 * 4);
    int* mncd = (int*)carve((size_t)KVOL * N1 * 4);
    int* mncu = (int*)carve((size_t)KVOL * N0 * 4);

    const int sz_in   = 2 * KVOL * 1 * 512;
    const int sz_enc1 = 2 * KVOL * 1 * 512;
    const int sz_down = 4 * KVOL * 1 * 512;
    const int sz_enc2 = 4 * KVOL * 2 * 512;
    const int sz_lat2 = 4 * KVOL * 2 * 512;
    const int sz_up2  = 2 * KVOL * 2 * 512;
    const int sz_lat1 = 2 * KVOL * 1 * 512;
    const int sz_up1  = 2 * KVOL * 1 * 512;
    const int sz_wm2  = 4 * 1 * 4 * 512;
    const int sz_wm1  = 2 * 1 * 2 * 512;

    bf16* Wp_in   = (bf16*)carve((size_t)sz_in * 2);
    bf16* Wp_enc1 = (bf16*)carve((size_t)sz_enc1 * 2);
    bf16* Wp_down = (bf16*)carve((size_t)sz_down * 2);
    bf16* Wp_enc2 = (bf16*)carve((size_t)sz_enc2 * 2);
    bf16* Wp_lat2 = (bf16*)carve((size_t)sz_lat2 * 2);
    bf16* Wp_up2  = (bf16*)carve((size_t)sz_up2 * 2);
    bf16* Wp_lat1 = (bf16*)carve((size_t)sz_lat1 * 2);
    bf16* Wp_up1  = (bf16*)carve((size_t)sz_up1 * 2);
    bf16* Wmp2    = (bf16*)carve((size_t)sz_wm2 * 2);
    bf16* Wmp1    = (bf16*)carve((size_t)sz_wm1 * 2);

    // --- prep ---
    cvt_pad_kernel<<<(N0 * 8 + 255) / 256, 256, 0, stream>>>(feat, featb, N0);

    {
        const int n0 = KVOL * N0, n1 = KVOL * N1;
        const int tot4 = (n0 + n1 + n1 + n0) / 4;
        mnc_all_kernel<<<(tot4 + 255) / 256, 256, 0, stream>>>(
            nbr0, mask0, mnc0, n0,
            nbr1, mask1, mnc1, n1,
            nbr_down, mask_down, mncd, n1,
            nbr_up, mask_up, mncu, n0, (int*)zp);
    }

    {
        PackJobs J;
        const float* Ws[10] = {W_in, W_enc1, W_down, W_enc2, W_lat2, W_up2, W_lat1, W_up1, W_merge2, W_merge1};
        bf16* Wps[10] = {Wp_in, Wp_enc1, Wp_down, Wp_enc2, Wp_lat2, Wp_up2, Wp_lat1, Wp_up1, Wmp2, Wmp1};
        const int cins[10]  = {16, 32, 32, 64, 64, 64, 32, 32, 128, 64};
        const int couts[10] = {32, 32, 64, 64, 64, 32, 32, 32, 64, 32};
        const int kvs[10]   = {KVOL, KVOL, KVOL, KVOL, KVOL, KVOL, KVOL, KVOL, 1, 1};
        const int szs[10]   = {sz_in, sz_enc1, sz_down, sz_enc2, sz_lat2, sz_up2, sz_lat1, sz_up1, sz_wm2, sz_wm1};
        int acc = 0;
        for (int i = 0; i < 10; ++i) {
            J.W[i] = Ws[i]; J.Wp[i] = Wps[i];
            J.cin[i] = cins[i]; J.cout[i] = couts[i]; J.kvol[i] = kvs[i];
            J.start[i] = acc; acc += szs[i];
        }
        J.start[10] = acc;
        pack_all_kernel<<<(acc + 255) / 256, 256, 0, stream>>>(J, acc);
    }

    // --- network ---
    // Nout=N0 CIN32 convs: WPB=2, RT=4, D=5/BR=6 (20 outstanding DMAs; R7
    //   isolates the depth hypothesis — host structure otherwise == R5).
    // Nout=N1 convs: RT=1, WPB=4.  up2: exactly R5 (D=3/BR=4, 5 blk/CU).
    launch_conv<32, 32, 2, 4, 2, 5, 6, 2, false>(featb, Wp_in, mnc0, zp, x0, N0, stream);
    launch_conv<32, 32, 2, 4, 2, 5, 6, 2, false>(x0, Wp_enc1, mnc0, zp, e1, N0, stream);
    launch_conv<32, 64, 2, 1, 4, 8, 8, 4, false>(e1, Wp_down, mncd, zp, xd, N1, stream);
    launch_conv<64, 64, 2, 1, 4, 6, 6, 3, false>(xd, Wp_enc2, mnc1, zp, e2, N1, stream);

    launch_conv<64, 64, 2, 1, 4, 6, 6, 3, false>(e2, Wp_lat2, mnc1, zp, xl2, N1, stream);
    launch_merge<64>(e2, xl2, Wmp2, m2, N1, stream);
    launch_conv<64, 32, 2, 2, 2, 3, 4, 2, false>(m2, Wp_up2, mncu, zp, u2, N0, stream);

    launch_conv<32, 32, 2, 4, 2, 5, 6, 2, false>(e1, Wp_lat1, mnc0, zp, xl1, N0, stream);
    launch_merge<32>(u2, xl1, Wmp1, m1, N0, stream);
    launch_conv<32, 32, 2, 4, 2, 5, 6, 2, true>(m1, Wp_up1, mnc0, zp, (float*)d_out, N0, stream);
}

// Round 8
// 191.320 us; speedup vs baseline: 1.1230x; 1.1230x over previous
//
#include <hip/hip_runtime.h>
#include <hip/hip_bf16.h>
#include <utility>

#define KVOL 27

using bf16 = __hip_bfloat16;
typedef __attribute__((ext_vector_type(8))) short short8;
typedef __attribute__((ext_vector_type(4))) short short4v;
typedef __attribute__((ext_vector_type(4))) float f32x4;
typedef __attribute__((ext_vector_type(4))) int int4v;

// async global->LDS 16B DMA; lds base is wave-uniform, HW writes lane i at base+i*16
__device__ __forceinline__ void async16(const void* g, void* l) {
    __builtin_amdgcn_global_load_lds(
        (const __attribute__((address_space(1))) void*)g,
        (__attribute__((address_space(3))) void*)l, 16, 0, 0);
}

template <class F, int... Is>
__device__ __forceinline__ void static_for_impl(F&& f, std::integer_sequence<int, Is...>) {
    (f(std::integral_constant<int, Is>{}), ...);
}
template <int N, class F>
__device__ __forceinline__ void static_for(F&& f) {
    static_for_impl(static_cast<F&&>(f), std::make_integer_sequence<int, N>{});
}

// vmcnt immediate guaranteeing stageA(t) complete (R3-proven form; the
// prologue branch is the order-robust lower bound on ops younger than SA(t)).
template <int NT, int D, int BR, int NI, int NB>
constexpr int waitA(int t) {
    int s = ((t + D < NT) ? NI : 0);            // SA(t+D), issued before the wait
    if (t < D) {
        for (int j = 0; j < t; ++j)
            s += ((j + D < NT) ? NI : 0) + ((j + BR < NT) ? NB : 0);
    } else {
        s += ((t - D + BR < NT) ? NB : 0);      // loadB tail of SA(t)'s region
        for (int j = t - D + 1; j < t; ++j)
            s += ((j + D < NT) ? NI : 0) + ((j + BR < NT) ? NB : 0);
    }
    return s;
}

// ---------------- fused prep: cvt_pad + mnc x4 + weight pack + zero page --
struct PackJobs {
    const float* W[10];
    bf16* Wp[10];
    int cin[10];
    int cout[10];
    int kvol[10];
    int start[11];
};

struct PrepArgs {
    const float* feat; bf16* featb; int n_cvt;          // N0*8 threads
    const int* nbr[4]; const int* mask[4]; int* mnc[4];
    int mnc_start[5];                                   // prefix, units of 4 ints
    PackJobs pj; int n_pack;
    int* zp;
};

__global__ __launch_bounds__(256) void prep_all_kernel(PrepArgs P) {
    if (blockIdx.x == 0 && threadIdx.x < 8) {
        int4v z = {0, 0, 0, 0};
        reinterpret_cast<int4v*>(P.zp)[threadIdx.x] = z;  // 128B zero page
    }
    int T = blockIdx.x * 256 + threadIdx.x;

    // --- job 1: fp32 -> bf16 convert, pad 16ch -> 32ch (4 elems/thread) ---
    if (T < P.n_cvt) {
        const int row = T >> 3;
        const int c4 = (T & 7) * 4;
        short4v o = {0, 0, 0, 0};
        if (c4 < 16) {
            const float4 v = *reinterpret_cast<const float4*>(P.feat + (size_t)row * 16 + c4);
            bf16 b0 = __float2bfloat16(v.x); o.x = *reinterpret_cast<short*>(&b0);
            bf16 b1 = __float2bfloat16(v.y); o.y = *reinterpret_cast<short*>(&b1);
            bf16 b2 = __float2bfloat16(v.z); o.z = *reinterpret_cast<short*>(&b2);
            bf16 b3 = __float2bfloat16(v.w); o.w = *reinterpret_cast<short*>(&b3);
        }
        *reinterpret_cast<short4v*>(P.featb + (size_t)row * 32 + c4) = o;
        return;
    }
    T -= P.n_cvt;

    // --- job 2: mnc compress (4 ints/thread) ---
    if (T < P.mnc_start[4]) {
        int tb = 3;
#pragma unroll
        for (int q = 2; q >= 0; --q) if (T < P.mnc_start[q + 1]) tb = q;
        const int off = (T - P.mnc_start[tb]) * 4;
        const int4v nb = *reinterpret_cast<const int4v*>(P.nbr[tb] + off);
        const int4v mk = *reinterpret_cast<const int4v*>(P.mask[tb] + off);
        int4v r;
        r.x = mk.x ? nb.x : -1;
        r.y = mk.y ? nb.y : -1;
        r.z = mk.z ? nb.z : -1;
        r.w = mk.w ? nb.w : -1;
        *reinterpret_cast<int4v*>(P.mnc[tb] + off) = r;
        return;
    }
    T -= P.mnc_start[4];

    // --- job 3: weight pack ---
    if (T < P.n_pack) {
        const PackJobs& J = P.pj;
        int jb = 9;
#pragma unroll
        for (int q = 8; q >= 0; --q) if (T < J.start[q + 1]) jb = q;
        const int u = T - J.start[jb];
        const int CIN = J.cin[jb], COUT = J.cout[jb], KV = J.kvol[jb];
        const int CINP = CIN < 32 ? 32 : CIN;
        const int NCH = CINP / 32;
        const int e = u & 7;
        const int lane = (u >> 3) & 63;
        int rest = u >> 9;
        const int c = rest % NCH; rest /= NCH;
        const int k = rest % KV;
        const int ct = rest / KV;
        const int cout = ct * 16 + (lane & 15);
        const int cin = c * 32 + (lane >> 4) * 8 + e;
        const float v = (cin < CIN) ? J.W[jb][((size_t)k * CIN + cin) * COUT + cout] : 0.f;
        J.Wp[jb][u] = __float2bfloat16(v);
    }
}

// ---------------- sparse conv: async-DMA staged, counted-vmcnt pipeline ---
// WPB independent waves/block; wave owns RT*16 rows x (CTW*16) cols over all
// 27 taps. A staged via global_load_lds (whole-line mapping, XOR swizzle on
// the per-lane GLOBAL source; linear LDS dest). Masked taps -> zero page.
// D-deep tap pipeline, compile-time vmcnt counts; B ring (BR>=D) refilled at
// region TAIL. setprio(1) around the MFMA nest (T5). No __syncthreads.
template <int CIN, int COUT, int CTW, int RT, int WPB, int D, int BR, int MINW, bool OUT_F32>
__global__ __launch_bounds__(WPB * 64, MINW) void conv_async_kernel(
    const bf16* __restrict__ x, const bf16* __restrict__ Wp,
    const int* __restrict__ mnc, const bf16* __restrict__ zp,
    void* __restrict__ outv, int Nout) {
    constexpr int NCH = CIN / 32;              // CIN in {32, 64}
    constexpr int CH  = CIN / 8;               // 16B chunks per row
    constexpr int RPI = 64 / CH;               // rows staged per instr
    constexpr int NI  = RT * NCH;              // stage instrs per tap
    constexpr int NB  = CTW * NCH;             // B loads per tap
    constexpr int ROWS = RT * 16;
    constexpr int SLOT = ROWS * CIN * 2;       // bytes per tap tile
    constexpr int NS = D + 1;
    constexpr int TPL = 64 / ROWS;             // taps per packed mnc load
    constexpr int NL = (KVOL + TPL - 1) / TPL;
    constexpr int CTG = (COUT / 16) / CTW;
    constexpr int NT = KVOL;

    __shared__ __align__(16) char smem[WPB][NS * SLOT];

    const int w = threadIdx.x >> 6;
    const int lane = threadIdx.x & 63;
    const int bid = blockIdx.x;
    const int rg = bid / CTG;
    const int cg = bid - rg * CTG;
    const int rowbase = rg * (WPB * ROWS) + w * ROWS;
    if (rowbase >= Nout) return;
    const int r = lane & 15;
    const int g = lane >> 4;
    char* const sb = smem[w];

    // packed mnc: load p covers taps p*TPL..p*TPL+TPL-1; lane = tp*ROWS + row
    int mnw[NL];
    {
        const int row = rowbase + (lane % ROWS);
        const int rc = (row < Nout) ? row : (Nout - 1);
#pragma unroll
        for (int p = 0; p < NL; ++p) {
            const int k = p * TPL + (lane / ROWS);
            int v = -1;
            if (k < NT) {
                const int vv = mnc[(size_t)k * Nout + rc];
                v = (row < Nout) ? vv : -1;
            }
            mnw[p] = v;
        }
    }

    short8 bring[BR][CTW][NCH];
    auto loadB = [&](int t) {
#pragma unroll
        for (int cw = 0; cw < CTW; ++cw) {
            const int ct = cg * CTW + cw;
#pragma unroll
            for (int c = 0; c < NCH; ++c)
                bring[t % BR][cw][c] = *reinterpret_cast<const short8*>(
                    Wp + (((size_t)ct * KVOL + t) * NCH + c) * 512 + lane * 8);
        }
    };

    auto stageA = [&](int t) {
        char* const dst = sb + (t % NS) * SLOT;
        const int mw = mnw[t / TPL];
        const int tb = (t % TPL) * ROWS;
        const int rl0 = lane / CH;             // row within stage instr
        const int ch0 = lane % CH;             // chunk within row
#pragma unroll
        for (int q = 0; q < NI; ++q) {
            const int rl = q * RPI + rl0;      // row within tile
            const int j = __builtin_amdgcn_ds_bpermute((tb + rl) * 4, mw);
            const int ch = (ch0 ^ (rl & (CH - 1))) * 8;        // XOR swizzle
            const bf16* src = (j >= 0) ? (x + (size_t)j * CIN) : zp;
            async16(src + ch, dst + q * 1024);
        }
    };

    f32x4 acc[RT][CTW];
#pragma unroll
    for (int rt = 0; rt < RT; ++rt)
#pragma unroll
        for (int cw = 0; cw < CTW; ++cw) {
            f32x4 z = {0.f, 0.f, 0.f, 0.f};
            acc[rt][cw] = z;
        }

    // prologue: BR B tiles first (older than all SA), then D A tiles
#pragma unroll
    for (int t = 0; t < BR; ++t) loadB(t);
#pragma unroll
    for (int t = 0; t < D; ++t) stageA(t);

    static_for<NT>([&](auto tc) {
        constexpr int t = decltype(tc)::value;
        // all prior ds_reads retired before their slot is re-DMA'd
        asm volatile("s_waitcnt lgkmcnt(0)" ::: "memory");
        if constexpr (t + D < NT) stageA(t + D);
        constexpr int WN = waitA<NT, D, BR, NI, NB>(t);
        asm volatile("s_waitcnt vmcnt(%0)" :: "n"(WN) : "memory");
        const char* sp = sb + (t % NS) * SLOT;
        short8 af[RT][NCH];
#pragma unroll
        for (int rt = 0; rt < RT; ++rt)
#pragma unroll
            for (int c = 0; c < NCH; ++c) {
                const int R = rt * 16 + r;
                const int cc = c * 4 + g;
                const int off = R * (CIN * 2) + ((cc ^ (R & (CH - 1))) * 16);
                af[rt][c] = *reinterpret_cast<const short8*>(sp + off);
            }
        __builtin_amdgcn_s_setprio(1);
#pragma unroll
        for (int c = 0; c < NCH; ++c)
#pragma unroll
            for (int cw = 0; cw < CTW; ++cw)
#pragma unroll
                for (int rt = 0; rt < RT; ++rt)
                    acc[rt][cw] = __builtin_amdgcn_mfma_f32_16x16x32_bf16(
                        af[rt][c], bring[t % BR][cw][c], acc[rt][cw], 0, 0, 0);
        __builtin_amdgcn_s_setprio(0);
        // ring refill AFTER last read of this slot (WAR, not RAW)
        if constexpr (t + BR < NT) loadB(t + BR);
    });

    // epilogue: wave owns its tile outright
#pragma unroll
    for (int rt = 0; rt < RT; ++rt)
#pragma unroll
        for (int cw = 0; cw < CTW; ++cw) {
            const int col = (cg * CTW + cw) * 16 + r;
#pragma unroll
            for (int i = 0; i < 4; ++i) {
                const int rowo = rowbase + rt * 16 + g * 4 + i;
                if (rowo < Nout) {
                    const float v = fmaxf(acc[rt][cw][i], 0.f);
                    if (OUT_F32) ((float*)outv)[(size_t)rowo * COUT + col] = v;
                    else ((bf16*)outv)[(size_t)rowo * COUT + col] = __float2bfloat16(v);
                }
            }
        }
}

// ---------------- decoder merge via MFMA ----------------
template <int C>
__global__ __launch_bounds__(256) void merge_mfma_kernel(
    const bf16* __restrict__ xb, const bf16* __restrict__ xl,
    const bf16* __restrict__ Wmp, bf16* __restrict__ out, int N) {
    constexpr int NCH = 2 * C / 32;
    constexpr int CT = C / 16;
    constexpr int CTW = 2;
    constexpr int CTG = CT / CTW;

    const int wid = blockIdx.x * (blockDim.x >> 6) + (threadIdx.x >> 6);
    const int lane = threadIdx.x & 63;
    const int rg = wid / CTG;
    const int cg = wid - rg * CTG;
    const int rowbase = rg * 16;
    if (rowbase >= N) return;
    const int r = lane & 15;
    const int g = lane >> 4;

    short8 a[NCH];
    const int arow = (rowbase + r < N) ? (rowbase + r) : (N - 1);
#pragma unroll
    for (int c = 0; c < NCH; ++c) {
        const int kbase = c * 32 + g * 8;
        const bf16* src = (kbase < C) ? (xb + (size_t)arow * C + kbase)
                                      : (xl + (size_t)arow * C + (kbase - C));
        a[c] = *reinterpret_cast<const short8*>(src);
    }

    f32x4 acc[CTW];
#pragma unroll
    for (int cw = 0; cw < CTW; ++cw) {
        f32x4 z = {0.f, 0.f, 0.f, 0.f};
        acc[cw] = z;
#pragma unroll
        for (int c = 0; c < NCH; ++c) {
            const size_t off = ((size_t)(cg * CTW + cw) * NCH + c) * 512 + lane * 8;
            const short8 b = *reinterpret_cast<const short8*>(Wmp + off);
            acc[cw] = __builtin_amdgcn_mfma_f32_16x16x32_bf16(a[c], b, acc[cw], 0, 0, 0);
        }
    }

#pragma unroll
    for (int cw = 0; cw < CTW; ++cw) {
        const int j = (cg * CTW + cw) * 16 + r;
#pragma unroll
        for (int i = 0; i < 4; ++i) {
            const int row = rowbase + g * 4 + i;
            if (row < N) {
                const float m = fmaxf(acc[cw][i], 0.f);
                const bf16* src = (2 * j < C) ? (xb + (size_t)row * C + 2 * j)
                                              : (xl + (size_t)row * C + (2 * j - C));
                const float red = __bfloat162float(src[0]) + __bfloat162float(src[1]);
                out[(size_t)row * C + j] = __float2bfloat16(m + red);
            }
        }
    }
}

// ---------------- host ----------------
template <int CIN, int COUT, int CTW, int RT, int WPB, int D, int BR, int MINW, bool OF32>
static void launch_conv(const bf16* x, const bf16* Wp, const int* mnc, const bf16* zp,
                        void* out, int Nout, hipStream_t s) {
    constexpr int CTG = (COUT / 16) / CTW;
    constexpr int BROWS = WPB * RT * 16;
    const int RG = (Nout + BROWS - 1) / BROWS;
    conv_async_kernel<CIN, COUT, CTW, RT, WPB, D, BR, MINW, OF32>
        <<<RG * CTG, WPB * 64, 0, s>>>(x, Wp, mnc, zp, out, Nout);
}

template <int C>
static void launch_merge(const bf16* xb, const bf16* xl, const bf16* Wmp,
                         bf16* out, int N, hipStream_t s) {
    constexpr int CTG = (C / 16) / 2;
    const int RG = (N + 15) / 16;
    const int waves = RG * CTG;
    const int blocks = (waves + 3) / 4;
    merge_mfma_kernel<C><<<blocks, 256, 0, s>>>(xb, xl, Wmp, out, N);
}

static size_t align_up(size_t v) { return (v + 255) & ~(size_t)255; }

extern "C" void kernel_launch(void* const* d_in, const int* in_sizes, int n_in,
                              void* d_out, int out_size, void* d_ws, size_t ws_size,
                              hipStream_t stream) {
    const float* feat     = (const float*)d_in[0];
    const int*   nbr0     = (const int*)d_in[1];
    const int*   mask0    = (const int*)d_in[2];
    const int*   nbr1     = (const int*)d_in[3];
    const int*   mask1    = (const int*)d_in[4];
    const int*   nbr_down = (const int*)d_in[5];
    const int*   mask_down= (const int*)d_in[6];
    const int*   nbr_up   = (const int*)d_in[7];
    const int*   mask_up  = (const int*)d_in[8];
    const float* W_in     = (const float*)d_in[9];
    const float* W_enc1   = (const float*)d_in[10];
    const float* W_down   = (const float*)d_in[11];
    const float* W_enc2   = (const float*)d_in[12];
    const float* W_lat2   = (const float*)d_in[13];
    const float* W_merge2 = (const float*)d_in[14];
    const float* W_up2    = (const float*)d_in[15];
    const float* W_lat1   = (const float*)d_in[16];
    const float* W_merge1 = (const float*)d_in[17];
    const float* W_up1    = (const float*)d_in[18];

    const int N0 = in_sizes[0] / 16;
    const int N1 = in_sizes[3] / KVOL;

    char* p = (char*)d_ws;
    auto carve = [&](size_t bytes) { char* q = p; p += align_up(bytes); return q; };

    bf16* featb = (bf16*)carve((size_t)N0 * 32 * 2);   // padded to 32 ch
    bf16* x0    = (bf16*)carve((size_t)N0 * 32 * 2);
    bf16* e1    = (bf16*)carve((size_t)N0 * 32 * 2);
    bf16* xd    = (bf16*)carve((size_t)N1 * 64 * 2);
    bf16* e2    = (bf16*)carve((size_t)N1 * 64 * 2);
    bf16* xl2   = (bf16*)carve((size_t)N1 * 64 * 2);
    bf16* m2    = (bf16*)carve((size_t)N1 * 64 * 2);
    bf16* u2    = (bf16*)carve((size_t)N0 * 32 * 2);
    bf16* xl1   = (bf16*)carve((size_t)N0 * 32 * 2);
    bf16* m1    = (bf16*)carve((size_t)N0 * 32 * 2);
    bf16* zp    = (bf16*)carve(256);                   // zero page (128B used)

    int* mnc0 = (int*)carve((size_t)KVOL * N0 * 4);
    int* mnc1 = (int*)carve((size_t)KVOL * N1 * 4);
    int* mncd = (int*)carve((size_t)KVOL * N1 * 4);
    int* mncu = (int*)carve((size_t)KVOL * N0 * 4);

    const int sz_in   = 2 * KVOL * 1 * 512;
    const int sz_enc1 = 2 * KVOL * 1 * 512;
    const int sz_down = 4 * KVOL * 1 * 512;
    const int sz_enc2 = 4 * KVOL * 2 * 512;
    const int sz_lat2 = 4 * KVOL * 2 * 512;
    const int sz_up2  = 2 * KVOL * 2 * 512;
    const int sz_lat1 = 2 * KVOL * 1 * 512;
    const int sz_up1  = 2 * KVOL * 1 * 512;
    const int sz_wm2  = 4 * 1 * 4 * 512;
    const int sz_wm1  = 2 * 1 * 2 * 512;

    bf16* Wp_in   = (bf16*)carve((size_t)sz_in * 2);
    bf16* Wp_enc1 = (bf16*)carve((size_t)sz_enc1 * 2);
    bf16* Wp_down = (bf16*)carve((size_t)sz_down * 2);
    bf16* Wp_enc2 = (bf16*)carve((size_t)sz_enc2 * 2);
    bf16* Wp_lat2 = (bf16*)carve((size_t)sz_lat2 * 2);
    bf16* Wp_up2  = (bf16*)carve((size_t)sz_up2 * 2);
    bf16* Wp_lat1 = (bf16*)carve((size_t)sz_lat1 * 2);
    bf16* Wp_up1  = (bf16*)carve((size_t)sz_up1 * 2);
    bf16* Wmp2    = (bf16*)carve((size_t)sz_wm2 * 2);
    bf16* Wmp1    = (bf16*)carve((size_t)sz_wm1 * 2);

    // --- fused prep (cvt + mnc x4 + pack + zero page), one dispatch ---
    {
        PrepArgs P;
        P.feat = feat; P.featb = featb; P.n_cvt = N0 * 8;
        const int* nbs[4] = {nbr0, nbr1, nbr_down, nbr_up};
        const int* mks[4] = {mask0, mask1, mask_down, mask_up};
        int* mns[4] = {mnc0, mnc1, mncd, mncu};
        const int szs4[4] = {KVOL * N0 / 4, KVOL * N1 / 4, KVOL * N1 / 4, KVOL * N0 / 4};
        int macc = 0;
        for (int i = 0; i < 4; ++i) {
            P.nbr[i] = nbs[i]; P.mask[i] = mks[i]; P.mnc[i] = mns[i];
            P.mnc_start[i] = macc; macc += szs4[i];
        }
        P.mnc_start[4] = macc;

        const float* Ws[10] = {W_in, W_enc1, W_down, W_enc2, W_lat2, W_up2, W_lat1, W_up1, W_merge2, W_merge1};
        bf16* Wps[10] = {Wp_in, Wp_enc1, Wp_down, Wp_enc2, Wp_lat2, Wp_up2, Wp_lat1, Wp_up1, Wmp2, Wmp1};
        const int cins[10]  = {16, 32, 32, 64, 64, 64, 32, 32, 128, 64};
        const int couts[10] = {32, 32, 64, 64, 64, 32, 32, 32, 64, 32};
        const int kvs[10]   = {KVOL, KVOL, KVOL, KVOL, KVOL, KVOL, KVOL, KVOL, 1, 1};
        const int szs[10]   = {sz_in, sz_enc1, sz_down, sz_enc2, sz_lat2, sz_up2, sz_lat1, sz_up1, sz_wm2, sz_wm1};
        int acc = 0;
        for (int i = 0; i < 10; ++i) {
            P.pj.W[i] = Ws[i]; P.pj.Wp[i] = Wps[i];
            P.pj.cin[i] = cins[i]; P.pj.cout[i] = couts[i]; P.pj.kvol[i] = kvs[i];
            P.pj.start[i] = acc; acc += szs[i];
        }
        P.pj.start[10] = acc;
        P.n_pack = acc;
        P.zp = (int*)zp;

        const int total = P.n_cvt + macc + acc;
        prep_all_kernel<<<(total + 255) / 256, 256, 0, stream>>>(P);
    }

    // --- network (R5-proven tilings; lat1 hoisted next to enc1 for L2 warmth) ---
    launch_conv<32, 32, 2, 4, 2, 3, 4, 2, false>(featb, Wp_in, mnc0, zp, x0, N0, stream);
    launch_conv<32, 32, 2, 4, 2, 3, 4, 2, false>(x0, Wp_enc1, mnc0, zp, e1, N0, stream);
    launch_conv<32, 32, 2, 4, 2, 3, 4, 2, false>(e1, Wp_lat1, mnc0, zp, xl1, N0, stream);
    launch_conv<32, 64, 2, 1, 4, 8, 8, 4, false>(e1, Wp_down, mncd, zp, xd, N1, stream);
    launch_conv<64, 64, 2, 1, 4, 5, 5, 3, false>(xd, Wp_enc2, mnc1, zp, e2, N1, stream);

    launch_conv<64, 64, 2, 1, 4, 5, 5, 3, false>(e2, Wp_lat2, mnc1, zp, xl2, N1, stream);
    launch_merge<64>(e2, xl2, Wmp2, m2, N1, stream);
    launch_conv<64, 32, 2, 2, 2, 3, 4, 2, false>(m2, Wp_up2, mncu, zp, u2, N0, stream);

    launch_merge<32>(u2, xl1, Wmp1, m1, N0, stream);
    launch_conv<32, 32, 2, 4, 2, 3, 4, 2, true>(m1, Wp_up1, mnc0, zp, (float*)d_out, N0, stream);
}